// Round 7
// baseline (297.233 us; speedup 1.0000x reference)
//
#include <hip/hip_runtime.h>
#include <math.h>

#define NUM_E 8
#define DIM 4096
#define THREADS 256
#define WAVES 4
#define VEC_ITERS (DIM / (THREADS * 4))   // 4
#define ROWS 2

typedef float f32x4 __attribute__((ext_vector_type(4)));

__device__ __forceinline__ f32x4 nt_load4(const float* p) {
    return __builtin_nontemporal_load(reinterpret_cast<const f32x4*>(p));
}
__device__ __forceinline__ void nt_store4(float* p, f32x4 v) {
    __builtin_nontemporal_store(v, reinterpret_cast<f32x4*>(p));
}

__global__ __launch_bounds__(THREADS, 8) void gate_dual_kernel(
    const float* __restrict__ x,        // [B, D]
    const float* __restrict__ experts,  // [B, NUM, D]
    const float* __restrict__ W,        // [NUM, D]
    float* __restrict__ out)            // [B, D]
{
    const int b0   = blockIdx.x * ROWS;
    const int t    = threadIdx.x;
    const int lane = t & 63;
    const int wave = t >> 6;

    __shared__ float red[ROWS][WAVES][NUM_E];

    // ---- prologue: gate dots for BOTH rows, sharing each W load ----
    const float* __restrict__ x0 = x + (size_t)b0 * DIM;
    const float* __restrict__ x1 = x + (size_t)(b0 + 1) * DIM;

    float p0[NUM_E], p1[NUM_E];
#pragma unroll
    for (int n = 0; n < NUM_E; ++n) { p0[n] = 0.0f; p1[n] = 0.0f; }

#pragma unroll
    for (int i = 0; i < VEC_ITERS; ++i) {
        const int d = (i * THREADS + t) * 4;
        const f32x4 x0v = nt_load4(x0 + d);
        const f32x4 x1v = nt_load4(x1 + d);
#pragma unroll
        for (int n = 0; n < NUM_E; ++n) {
            const f32x4 wv = *reinterpret_cast<const f32x4*>(W + n * DIM + d);
            p0[n] += x0v.x * wv.x + x0v.y * wv.y + x0v.z * wv.z + x0v.w * wv.w;
            p1[n] += x1v.x * wv.x + x1v.y * wv.y + x1v.z * wv.z + x1v.w * wv.w;
        }
    }

    // ---- one butterfly reduce + one barrier for both rows ----
#pragma unroll
    for (int n = 0; n < NUM_E; ++n) {
#pragma unroll
        for (int off = 32; off > 0; off >>= 1) {
            p0[n] += __shfl_down(p0[n], off, 64);
            p1[n] += __shfl_down(p1[n], off, 64);
        }
    }
    if (lane == 0) {
#pragma unroll
        for (int n = 0; n < NUM_E; ++n) {
            red[0][wave][n] = p0[n];
            red[1][wave][n] = p1[n];
        }
    }
    __syncthreads();

    // ---- softmax for both rows (redundant per thread, 8-wide each) ----
    float wgt0[NUM_E], wgt1[NUM_E];
    {
#pragma unroll
        for (int n = 0; n < NUM_E; ++n) {
            wgt0[n] = red[0][0][n] + red[0][1][n] + red[0][2][n] + red[0][3][n];
            wgt1[n] = red[1][0][n] + red[1][1][n] + red[1][2][n] + red[1][3][n];
        }
        float m0 = wgt0[0], m1 = wgt1[0];
#pragma unroll
        for (int n = 1; n < NUM_E; ++n) {
            m0 = fmaxf(m0, wgt0[n]);
            m1 = fmaxf(m1, wgt1[n]);
        }
        float s0 = 0.0f, s1 = 0.0f;
#pragma unroll
        for (int n = 0; n < NUM_E; ++n) {
            wgt0[n] = __expf(wgt0[n] - m0); s0 += wgt0[n];
            wgt1[n] = __expf(wgt1[n] - m1); s1 += wgt1[n];
        }
        const float i0 = 1.0f / s0, i1 = 1.0f / s1;
#pragma unroll
        for (int n = 0; n < NUM_E; ++n) { wgt0[n] *= i0; wgt1[n] *= i1; }
    }

    // ---- combine row 0: pure n-outer sequential stream ----
    {
        const float* __restrict__ e0 = experts + (size_t)b0 * NUM_E * DIM;
        float* __restrict__ o0 = out + (size_t)b0 * DIM;
        f32x4 acc[VEC_ITERS];
#pragma unroll
        for (int i = 0; i < VEC_ITERS; ++i) acc[i] = (f32x4)(0.0f);
#pragma unroll
        for (int n = 0; n < NUM_E; ++n) {
            const float wn = wgt0[n];
#pragma unroll
            for (int i = 0; i < VEC_ITERS; ++i) {
                const f32x4 ev = nt_load4(e0 + (size_t)n * DIM + (i * THREADS + t) * 4);
                acc[i].x += wn * ev.x;
                acc[i].y += wn * ev.y;
                acc[i].z += wn * ev.z;
                acc[i].w += wn * ev.w;
            }
        }
#pragma unroll
        for (int i = 0; i < VEC_ITERS; ++i)
            nt_store4(o0 + (i * THREADS + t) * 4, acc[i]);
    }

    // ---- combine row 1 ----
    {
        const float* __restrict__ e1 = experts + (size_t)(b0 + 1) * NUM_E * DIM;
        float* __restrict__ o1 = out + (size_t)(b0 + 1) * DIM;
        f32x4 acc[VEC_ITERS];
#pragma unroll
        for (int i = 0; i < VEC_ITERS; ++i) acc[i] = (f32x4)(0.0f);
#pragma unroll
        for (int n = 0; n < NUM_E; ++n) {
            const float wn = wgt1[n];
#pragma unroll
            for (int i = 0; i < VEC_ITERS; ++i) {
                const f32x4 ev = nt_load4(e1 + (size_t)n * DIM + (i * THREADS + t) * 4);
                acc[i].x += wn * ev.x;
                acc[i].y += wn * ev.y;
                acc[i].z += wn * ev.z;
                acc[i].w += wn * ev.w;
            }
        }
#pragma unroll
        for (int i = 0; i < VEC_ITERS; ++i)
            nt_store4(o1 + (i * THREADS + t) * 4, acc[i]);
    }
}

extern "C" void kernel_launch(void* const* d_in, const int* in_sizes, int n_in,
                              void* d_out, int out_size, void* d_ws, size_t ws_size,
                              hipStream_t stream) {
    const float* x       = (const float*)d_in[0];
    const float* experts = (const float*)d_in[1];
    const float* W       = (const float*)d_in[2];
    float* out           = (float*)d_out;

    const int B = in_sizes[0] / DIM;   // 8192

    gate_dual_kernel<<<B / ROWS, THREADS, 0, stream>>>(x, experts, W, out);
}

// Round 8
// 264.849 us; speedup vs baseline: 1.1223x; 1.1223x over previous
//
#include <hip/hip_runtime.h>
#include <math.h>

#define NUM_E 8
#define DIM 4096
#define THREADS 256
#define WAVES 4
#define VEC_ITERS (DIM / (THREADS * 4))   // 4
#define ROWS 4

typedef float f32x4 __attribute__((ext_vector_type(4)));

__device__ __forceinline__ f32x4 nt_load4(const float* p) {
    return __builtin_nontemporal_load(reinterpret_cast<const f32x4*>(p));
}
__device__ __forceinline__ void nt_store4(float* p, f32x4 v) {
    __builtin_nontemporal_store(v, reinterpret_cast<f32x4*>(p));
}

// wave butterfly reduce + cross-wave LDS reduce + 8-wide softmax (redundant/thread)
__device__ __forceinline__ void reduce_softmax(float p[NUM_E],
                                               float (*red)[NUM_E],
                                               int lane, int wave,
                                               float wgt[NUM_E],
                                               bool pre_barrier)
{
#pragma unroll
    for (int n = 0; n < NUM_E; ++n) {
#pragma unroll
        for (int off = 32; off > 0; off >>= 1)
            p[n] += __shfl_down(p[n], off, 64);
    }
    if (pre_barrier) __syncthreads();   // WAR protection on red reuse
    if (lane == 0) {
#pragma unroll
        for (int n = 0; n < NUM_E; ++n) red[wave][n] = p[n];
    }
    __syncthreads();
#pragma unroll
    for (int n = 0; n < NUM_E; ++n)
        wgt[n] = red[0][n] + red[1][n] + red[2][n] + red[3][n];
    float m = wgt[0];
#pragma unroll
    for (int n = 1; n < NUM_E; ++n) m = fmaxf(m, wgt[n]);
    float sum = 0.0f;
#pragma unroll
    for (int n = 0; n < NUM_E; ++n) {
        wgt[n] = __expf(wgt[n] - m);
        sum += wgt[n];
    }
    const float inv = 1.0f / sum;
#pragma unroll
    for (int n = 0; n < NUM_E; ++n) wgt[n] *= inv;
}

__global__ __launch_bounds__(THREADS) void gate_pipelined_kernel(
    const float* __restrict__ x,        // [B, D]
    const float* __restrict__ experts,  // [B, NUM, D]
    const float* __restrict__ W,        // [NUM, D]
    float* __restrict__ out)            // [B, D]
{
    const int b0   = blockIdx.x * ROWS;
    const int t    = threadIdx.x;
    const int lane = t & 63;
    const int wave = t >> 6;

    __shared__ float red[WAVES][NUM_E];

    // ---- prologue: gate dot for row 0 (only unhidden gate work) ----
    {
        const float* __restrict__ x0 = x + (size_t)b0 * DIM;
        float p[NUM_E];
#pragma unroll
        for (int n = 0; n < NUM_E; ++n) p[n] = 0.0f;
#pragma unroll
        for (int i = 0; i < VEC_ITERS; ++i) {
            const int d = (i * THREADS + t) * 4;
            const f32x4 xv = nt_load4(x0 + d);
#pragma unroll
            for (int n = 0; n < NUM_E; ++n) {
                const f32x4 wv = *reinterpret_cast<const f32x4*>(W + n * DIM + d);
                p[n] += xv.x * wv.x + xv.y * wv.y + xv.z * wv.z + xv.w * wv.w;
            }
        }
        float wgt_tmp[NUM_E];
        reduce_softmax(p, red, lane, wave, wgt_tmp, false);
        // stash into wgt_cur
#pragma unroll
        for (int n = 0; n < NUM_E; ++n) p[n] = wgt_tmp[n];
        // fallthrough via registers below
        float wgt_cur[NUM_E];
#pragma unroll
        for (int n = 0; n < NUM_E; ++n) wgt_cur[n] = p[n];

        // ---- pipelined rows: combine(r) with gate(r+1) interleaved ----
#pragma unroll
        for (int r = 0; r < ROWS; ++r) {
            const float* __restrict__ er = experts + (size_t)(b0 + r) * NUM_E * DIM;
            float* __restrict__ orow = out + (size_t)(b0 + r) * DIM;

            f32x4 acc[VEC_ITERS];
#pragma unroll
            for (int i = 0; i < VEC_ITERS; ++i) acc[i] = (f32x4)(0.0f);

            if (r + 1 < ROWS) {
                // hoist next row's x into registers
                const float* __restrict__ xn = x + (size_t)(b0 + r + 1) * DIM;
                f32x4 xv[VEC_ITERS];
#pragma unroll
                for (int i = 0; i < VEC_ITERS; ++i)
                    xv[i] = nt_load4(xn + (i * THREADS + t) * 4);

                float pn[NUM_E];
#pragma unroll
                for (int n = 0; n < NUM_E; ++n) pn[n] = 0.0f;

#pragma unroll
                for (int n = 0; n < NUM_E; ++n) {
                    const float wn = wgt_cur[n];
#pragma unroll
                    for (int i = 0; i < VEC_ITERS; ++i) {
                        const int d = (i * THREADS + t) * 4;
                        const f32x4 ev = nt_load4(er + (size_t)n * DIM + d);
                        acc[i].x += wn * ev.x;
                        acc[i].y += wn * ev.y;
                        acc[i].z += wn * ev.z;
                        acc[i].w += wn * ev.w;
                        // next row's gate work (W from L2, hidden under stream)
                        const f32x4 wv = *reinterpret_cast<const f32x4*>(W + n * DIM + d);
                        pn[n] += xv[i].x * wv.x + xv[i].y * wv.y
                               + xv[i].z * wv.z + xv[i].w * wv.w;
                    }
                }
#pragma unroll
                for (int i = 0; i < VEC_ITERS; ++i)
                    nt_store4(orow + (i * THREADS + t) * 4, acc[i]);

                reduce_softmax(pn, red, lane, wave, wgt_cur, true);
            } else {
                // last row: pure stream
#pragma unroll
                for (int n = 0; n < NUM_E; ++n) {
                    const float wn = wgt_cur[n];
#pragma unroll
                    for (int i = 0; i < VEC_ITERS; ++i) {
                        const int d = (i * THREADS + t) * 4;
                        const f32x4 ev = nt_load4(er + (size_t)n * DIM + d);
                        acc[i].x += wn * ev.x;
                        acc[i].y += wn * ev.y;
                        acc[i].z += wn * ev.z;
                        acc[i].w += wn * ev.w;
                    }
                }
#pragma unroll
                for (int i = 0; i < VEC_ITERS; ++i)
                    nt_store4(orow + (i * THREADS + t) * 4, acc[i]);
            }
        }
    }
}

extern "C" void kernel_launch(void* const* d_in, const int* in_sizes, int n_in,
                              void* d_out, int out_size, void* d_ws, size_t ws_size,
                              hipStream_t stream) {
    const float* x       = (const float*)d_in[0];
    const float* experts = (const float*)d_in[1];
    const float* W       = (const float*)d_in[2];
    float* out           = (float*)d_out;

    const int B = in_sizes[0] / DIM;   // 8192

    gate_pipelined_kernel<<<B / ROWS, THREADS, 0, stream>>>(x, experts, W, out);
}

// Round 9
// 233.743 us; speedup vs baseline: 1.2716x; 1.1331x over previous
//
#include <hip/hip_runtime.h>
#include <math.h>

#define NUM_E 8
#define DIM 4096
#define THREADS 256
#define WAVES 4
#define VEC_ITERS (DIM / (THREADS * 4))   // 4
#define ROWS 2

typedef float f32x4 __attribute__((ext_vector_type(4)));

__device__ __forceinline__ f32x4 nt_load4(const float* p) {
    return __builtin_nontemporal_load(reinterpret_cast<const f32x4*>(p));
}
__device__ __forceinline__ void nt_store4(float* p, f32x4 v) {
    __builtin_nontemporal_store(v, reinterpret_cast<f32x4*>(p));
}

// wave butterfly reduce + cross-wave LDS reduce + 8-wide softmax (redundant/thread)
__device__ __forceinline__ void reduce_softmax(float p[NUM_E],
                                               float (*red)[NUM_E],
                                               int lane, int wave,
                                               float wgt[NUM_E])
{
#pragma unroll
    for (int n = 0; n < NUM_E; ++n) {
#pragma unroll
        for (int off = 32; off > 0; off >>= 1)
            p[n] += __shfl_down(p[n], off, 64);
    }
    if (lane == 0) {
#pragma unroll
        for (int n = 0; n < NUM_E; ++n) red[wave][n] = p[n];
    }
    __syncthreads();
#pragma unroll
    for (int n = 0; n < NUM_E; ++n)
        wgt[n] = red[0][n] + red[1][n] + red[2][n] + red[3][n];
    float m = wgt[0];
#pragma unroll
    for (int n = 1; n < NUM_E; ++n) m = fmaxf(m, wgt[n]);
    float sum = 0.0f;
#pragma unroll
    for (int n = 0; n < NUM_E; ++n) {
        wgt[n] = __expf(wgt[n] - m);
        sum += wgt[n];
    }
    const float inv = 1.0f / sum;
#pragma unroll
    for (int n = 0; n < NUM_E; ++n) wgt[n] *= inv;
}

__global__ __launch_bounds__(THREADS) void gate_pipelined_kernel(
    const float* __restrict__ x,        // [B, D]
    const float* __restrict__ experts,  // [B, NUM, D]
    const float* __restrict__ W,        // [NUM, D]
    float* __restrict__ out)            // [B, D]
{
    const int b0   = blockIdx.x * ROWS;
    const int t    = threadIdx.x;
    const int lane = t & 63;
    const int wave = t >> 6;

    // double-buffered reduce scratch: row0 -> red[0], row1 -> red[1] (no WAR barrier)
    __shared__ float red[ROWS][WAVES][NUM_E];

    // ---- prologue: gate dot for row 0 ----
    const float* __restrict__ x0 = x + (size_t)b0 * DIM;
    float p[NUM_E];
#pragma unroll
    for (int n = 0; n < NUM_E; ++n) p[n] = 0.0f;
#pragma unroll
    for (int i = 0; i < VEC_ITERS; ++i) {
        const int d = (i * THREADS + t) * 4;
        const f32x4 xv = nt_load4(x0 + d);
#pragma unroll
        for (int n = 0; n < NUM_E; ++n) {
            const f32x4 wv = *reinterpret_cast<const f32x4*>(W + n * DIM + d);
            p[n] += xv.x * wv.x + xv.y * wv.y + xv.z * wv.z + xv.w * wv.w;
        }
    }
    float wgt0[NUM_E];
    reduce_softmax(p, red[0], lane, wave, wgt0);

    // ---- combine row 0 (n-outer sequential sweep) + row 1 gate interleaved ----
    const float* __restrict__ e0 = experts + (size_t)b0 * NUM_E * DIM;
    float* __restrict__ o0 = out + (size_t)b0 * DIM;
    const float* __restrict__ x1 = x + (size_t)(b0 + 1) * DIM;

    // hoist row-1 x into registers (16 VGPRs)
    f32x4 xv[VEC_ITERS];
#pragma unroll
    for (int i = 0; i < VEC_ITERS; ++i)
        xv[i] = nt_load4(x1 + (i * THREADS + t) * 4);

    float p1[NUM_E];
#pragma unroll
    for (int n = 0; n < NUM_E; ++n) p1[n] = 0.0f;

    f32x4 acc[VEC_ITERS];
#pragma unroll
    for (int i = 0; i < VEC_ITERS; ++i) acc[i] = (f32x4)(0.0f);

#pragma unroll
    for (int n = 0; n < NUM_E; ++n) {
        const float wn = wgt0[n];
#pragma unroll
        for (int i = 0; i < VEC_ITERS; ++i) {
            const int d = (i * THREADS + t) * 4;
            const f32x4 ev = nt_load4(e0 + (size_t)n * DIM + d);
            acc[i].x += wn * ev.x;
            acc[i].y += wn * ev.y;
            acc[i].z += wn * ev.z;
            acc[i].w += wn * ev.w;
            // row-1 gate work (W from L2, rides under the stream)
            const f32x4 wv = *reinterpret_cast<const f32x4*>(W + n * DIM + d);
            p1[n] += xv[i].x * wv.x + xv[i].y * wv.y + xv[i].z * wv.z + xv[i].w * wv.w;
        }
    }
#pragma unroll
    for (int i = 0; i < VEC_ITERS; ++i)
        nt_store4(o0 + (i * THREADS + t) * 4, acc[i]);

    float wgt1[NUM_E];
    reduce_softmax(p1, red[1], lane, wave, wgt1);

    // ---- combine row 1 (n-outer, sequential sweep) ----
    const float* __restrict__ e1 = experts + (size_t)(b0 + 1) * NUM_E * DIM;
    float* __restrict__ o1 = out + (size_t)(b0 + 1) * DIM;

#pragma unroll
    for (int i = 0; i < VEC_ITERS; ++i) acc[i] = (f32x4)(0.0f);

#pragma unroll
    for (int n = 0; n < NUM_E; ++n) {
        const float wn = wgt1[n];
#pragma unroll
        for (int i = 0; i < VEC_ITERS; ++i) {
            const int d = (i * THREADS + t) * 4;
            const f32x4 ev = nt_load4(e1 + (size_t)n * DIM + d);
            acc[i].x += wn * ev.x;
            acc[i].y += wn * ev.y;
            acc[i].z += wn * ev.z;
            acc[i].w += wn * ev.w;
        }
    }
#pragma unroll
    for (int i = 0; i < VEC_ITERS; ++i)
        nt_store4(o1 + (i * THREADS + t) * 4, acc[i]);
}

extern "C" void kernel_launch(void* const* d_in, const int* in_sizes, int n_in,
                              void* d_out, int out_size, void* d_ws, size_t ws_size,
                              hipStream_t stream) {
    const float* x       = (const float*)d_in[0];
    const float* experts = (const float*)d_in[1];
    const float* W       = (const float*)d_in[2];
    float* out           = (float*)d_out;

    const int B = in_sizes[0] / DIM;   // 8192

    gate_pipelined_kernel<<<B / ROWS, THREADS, 0, stream>>>(x, experts, W, out);
}